// Round 10
// baseline (210.309 us; speedup 1.0000x reference)
//
#include <hip/hip_runtime.h>
#include <hip/hip_bf16.h>

typedef short s8v __attribute__((ext_vector_type(8)));   // 8 bf16 (4 VGPRs) MFMA A/B frag
typedef float f4v __attribute__((ext_vector_type(4)));   // 4 fp32 MFMA C/D frag

__device__ __forceinline__ unsigned int bfround(float f) {
    unsigned int x = __float_as_uint(f);
    return (x + 0x7fffu + ((x >> 16) & 1u)) >> 16;  // RNE fp32->bf16
}
// packed RNE fp32x2 -> bf16x2 (v_cvt_pk_bf16_f32 on gfx950)
__device__ __forceinline__ unsigned int pkbf(float x, float y) {
    __hip_bfloat162 h = __float22bfloat162_rn(make_float2(x, y));
    return *(unsigned int*)&h;
}
// signed-int8 extract byte k of word w -> float  (v_bfe_i32 + v_cvt_f32_i32)
__device__ __forceinline__ float i8f(unsigned int w, int k) {
    return (float)((int)(signed char)(w >> (8 * k)));
}

// Pack W1 (fp32, [256x128]) into bf16 MFMA B-fragments laid out per-lane so proj
// waves read them with fully-coalesced uint4 loads.
// WF[half][c][t][lane] : uint4 = 8 bf16, j=0..7, k = c*32 + (lane>>4)*8 + j, col = t*16 + (lane&15)
__global__ __launch_bounds__(256) void pack_w(const float* __restrict__ W1,
                                              uint4* __restrict__ WF)
{
    const int half = blockIdx.x;
    #pragma unroll
    for (int iter = 0; iter < 8; ++iter) {
        int idx  = iter * 256 + threadIdx.x;   // (c,t,lane) flattened
        int lane = idx & 63;
        int t    = (idx >> 6) & 7;
        int c    = idx >> 9;
        int q = lane >> 4, m = lane & 15;
        unsigned int w[4];
        #pragma unroll
        for (int jj = 0; jj < 4; ++jj) {
            float lo = W1[(size_t)(half * 128 + c * 32 + q * 8 + 2 * jj    ) * 128 + t * 16 + m];
            float hi = W1[(size_t)(half * 128 + c * 32 + q * 8 + 2 * jj + 1) * 128 + t * 16 + m];
            w[jj] = bfround(lo) | (bfround(hi) << 16);
        }
        WF[(size_t)half * 2048 + idx] = make_uint4(w[0], w[1], w[2], w[3]);
    }
}

// Projection v6: persistent waves; W fragments register/AGPR-resident (loaded once,
// coalesced); depth-2 A prefetch (miss latency ~900cyc > per-tile compute ~600cyc,
// so depth-1 was insufficient); full-line coalesced scale stores.
// Blocks [0,bph)=users, [bph,2bph)=movies. int8 rows + per-row fp32 scale,
// column perm(t*16+m) = m*8+t (edge kernel indexes W2 identically).
__global__ __launch_bounds__(256, 2) void proj_kernel(
    const float* __restrict__ userf, const float* __restrict__ movief,
    const uint4* __restrict__ WF, const float* __restrict__ b1,
    uint2* __restrict__ Pu, uint2* __restrict__ Pm,
    float* __restrict__ SU, float* __restrict__ SM,
    int ntiles, int bph)
{
    const int half = blockIdx.x >= bph;
    const int bid  = half ? blockIdx.x - bph : blockIdx.x;
    const float* __restrict__ feat = half ? movief : userf;
    uint2* __restrict__ P = half ? Pm : Pu;
    float* __restrict__ S = half ? SM : SU;
    const uint4* __restrict__ wfh = WF + (size_t)half * 2048;

    const int lane = threadIdx.x & 63;
    const int m    = lane & 15;
    const int q    = lane >> 4;

    // One-time: all 32 B-fragments, 32 coalesced uint4 loads (live in unified
    // VGPR/AGPR file for the whole kernel).
    s8v bfrag[8][4];
    #pragma unroll
    for (int c = 0; c < 4; ++c)
        #pragma unroll
        for (int t = 0; t < 8; ++t) {
            uint4 f = wfh[(c * 8 + t) * 64 + lane];
            bfrag[t][c] = *(const s8v*)&f;
        }

    float bias_v[8];
    #pragma unroll
    for (int t = 0; t < 8; ++t)
        bias_v[t] = half ? b1[t * 16 + m] : 0.0f;

    const int wid = bid * 4 + (threadIdx.x >> 6);   // wave id within half
    const int nw  = bph * 4;                        // waves per half

#define LOAD_A(dst, t_) do {                                            \
        const float4* arow_ = (const float4*)feat + (size_t)(t_) * 512; \
        _Pragma("unroll")                                               \
        for (int c_ = 0; c_ < 4; ++c_) {                                \
            dst[c_][0] = arow_[m * 32 + c_ * 8 + q * 2 + 0];            \
            dst[c_][1] = arow_[m * 32 + c_ * 8 + q * 2 + 1];            \
        }                                                               \
    } while (0)

    float4 a0[4][2], a1[4][2], a2[4][2];
    int tile = wid;
    if (tile < ntiles)          LOAD_A(a0, tile);
    if (tile + nw < ntiles)     LOAD_A(a1, tile + nw);

    while (tile < ntiles) {
        const int pf = tile + 2 * nw;
        if (pf < ntiles) LOAD_A(a2, pf);   // depth-2: in flight across this tile + next

        f4v acc[8];
        #pragma unroll
        for (int t = 0; t < 8; ++t)
            acc[t] = (f4v){bias_v[t], bias_v[t], bias_v[t], bias_v[t]};

        #pragma unroll
        for (int c = 0; c < 4; ++c) {
            uint4 aw;
            aw.x = pkbf(a0[c][0].x, a0[c][0].y);
            aw.y = pkbf(a0[c][0].z, a0[c][0].w);
            aw.z = pkbf(a0[c][1].x, a0[c][1].y);
            aw.w = pkbf(a0[c][1].z, a0[c][1].w);
            s8v af = *(const s8v*)&aw;

            #pragma unroll
            for (int t = 0; t < 8; ++t)
                acc[t] = __builtin_amdgcn_mfma_f32_16x16x32_bf16(af, bfrag[t][c], acc[t], 0, 0, 0);
        }

        // C/D layout: col = t*16+m, row = q*4+r  [m89/m91 verified]. int8-quantize
        // each row; absmax over the 16-lane m-group (xor 1..8 stays in-group).
        float snv[4];
        #pragma unroll
        for (int r = 0; r < 4; ++r) {
            float mx = 0.0f;
            #pragma unroll
            for (int t = 0; t < 8; ++t) mx = fmaxf(mx, fabsf(acc[t][r]));
            #pragma unroll
            for (int off = 1; off < 16; off <<= 1)
                mx = fmaxf(mx, __shfl_xor(mx, off, 64));
            float inv = mx > 0.0f ? 127.0f / mx : 0.0f;
            snv[r] = mx * (1.0f / 127.0f);

            unsigned int lo = 0, hi = 0;
            #pragma unroll
            for (int t = 0; t < 4; ++t) {
                lo |= ((unsigned int)(__float2int_rn(acc[t][r]     * inv) & 0xff)) << (8 * t);
                hi |= ((unsigned int)(__float2int_rn(acc[t + 4][r] * inv) & 0xff)) << (8 * t);
            }
            int row = tile * 16 + q * 4 + r;
            P[(size_t)row * 16 + m] = make_uint2(lo, hi);  // 16 lanes x 8B = one 128B row
        }

        // Coalesced scale store: lane L<16 writes S[tile*16+L] -> one full 64B line.
        // Row L lives in q-group L>>2, iteration r=L&3; snv uniform within m-group.
        {
            float t0 = __shfl(snv[0], (lane >> 2 & 3) << 4, 64);
            float t1 = __shfl(snv[1], (lane >> 2 & 3) << 4, 64);
            float t2 = __shfl(snv[2], (lane >> 2 & 3) << 4, 64);
            float t3 = __shfl(snv[3], (lane >> 2 & 3) << 4, 64);
            float v01 = (lane & 1) ? t1 : t0;
            float v23 = (lane & 1) ? t3 : t2;
            float val = (lane & 2) ? v23 : v01;
            if (lane < 16) S[tile * 16 + lane] = val;
        }

        #pragma unroll
        for (int c = 0; c < 4; ++c) {
            a0[c][0] = a1[c][0]; a0[c][1] = a1[c][1];
            a1[c][0] = a2[c][0]; a1[c][1] = a2[c][1];
        }
        tile += nw;
    }
#undef LOAD_A
}

// out[e] = relu(su*Qu[src] + sm*Qm[dst]) . W2 + b2   (b1 folded into Pm; perm'd dims)
// 16 lanes/edge (uint2 = 8 int8 dims per lane), 16 edges/wave.
__global__ __launch_bounds__(256) void edge_kernel(
    const int* __restrict__ src, const int* __restrict__ dst,
    const uint2* __restrict__ Pu, const uint2* __restrict__ Pm,
    const float* __restrict__ SU, const float* __restrict__ SM,
    const float* __restrict__ W2, const float* __restrict__ b2,
    float* __restrict__ out)
{
    const int lane = threadIdx.x & 63;
    const int L    = lane & 15;      // sub-lane within edge group
    const int g    = lane >> 4;      // edge group 0..3
    const int eg   = (blockIdx.x * 4 + (threadIdx.x >> 6)) * 16 + g * 4;

    // W2 at perm position L*8+j is original col j*16+L
    float w2v[8];
    #pragma unroll
    for (int j = 0; j < 8; ++j) w2v[j] = W2[j * 16 + L];

    int si[4], di[4];
    #pragma unroll
    for (int i = 0; i < 4; ++i) { si[i] = src[eg + i]; di[i] = dst[eg + i]; }

    uint2 pu[4], pm[4];
    float scu[4], scm[4];
    #pragma unroll
    for (int i = 0; i < 4; ++i) {
        pu[i] = Pu[(size_t)si[i] * 16 + L];   // 8B/lane, one 128B line per 16-lane group
        pm[i] = Pm[(size_t)di[i] * 16 + L];
        scu[i] = SU[si[i]];                   // 400KB arrays, L2-resident
        scm[i] = SM[di[i]];
    }

    float res[4];
    #pragma unroll
    for (int i = 0; i < 4; ++i) {
        const unsigned int uw[2] = {pu[i].x, pu[i].y};
        const unsigned int mw[2] = {pm[i].x, pm[i].y};
        float acc = 0.0f;
        #pragma unroll
        for (int v = 0; v < 2; ++v) {
            #pragma unroll
            for (int k = 0; k < 4; ++k) {
                float h = fmaf(scu[i], i8f(uw[v], k), scm[i] * i8f(mw[v], k));
                acc = fmaf(fmaxf(h, 0.0f), w2v[v * 4 + k], acc);
            }
        }
        #pragma unroll
        for (int off = 1; off < 16; off <<= 1)
            acc += __shfl_xor(acc, off, 64);
        res[i] = acc;
    }

    if (L == 0) {
        float bb = b2[0];
        *(float4*)(out + eg) = make_float4(res[0] + bb, res[1] + bb, res[2] + bb, res[3] + bb);
    }
}

extern "C" void kernel_launch(void* const* d_in, const int* in_sizes, int n_in,
                              void* d_out, int out_size, void* d_ws, size_t ws_size,
                              hipStream_t stream) {
    const float* userf  = (const float*)d_in[0];
    const float* movief = (const float*)d_in[1];
    const int*   eidx   = (const int*)d_in[2];
    const float* W1     = (const float*)d_in[3];
    const float* b1     = (const float*)d_in[4];
    const float* W2     = (const float*)d_in[5];
    const float* b2     = (const float*)d_in[6];
    float* out = (float*)d_out;

    const int NU = in_sizes[0] / 128;   // 100000
    const int NM = in_sizes[1] / 128;   // 100000
    const int E  = in_sizes[2] / 2;     // 1000000

    // Workspace: Qu 12.8MB | Qm 12.8MB | SU 400KB | SM 400KB | WF 64KB
    uint2* Pu = (uint2*)d_ws;
    uint2* Pm = Pu + (size_t)NU * 16;
    float* SU = (float*)(Pm + (size_t)NM * 16);
    float* SM = SU + NU;
    uint4* WF = (uint4*)(SM + NM);

    const int ntiles = NU / 16;   // 6250 per half
    const int bph    = 512;       // 2048 waves/half, ~3 tiles/wave

    pack_w<<<2, 256, 0, stream>>>(W1, WF);
    proj_kernel<<<2 * bph, 256, 0, stream>>>(userf, movief, WF, b1, Pu, Pm, SU, SM, ntiles, bph);
    edge_kernel<<<E / 64, 256, 0, stream>>>(eidx, eidx + E, Pu, Pm, SU, SM, W2, b2, out);
}